// Round 2
// baseline (358.179 us; speedup 1.0000x reference)
//
#include <hip/hip_runtime.h>
#include <hip/hip_bf16.h>

typedef __attribute__((ext_vector_type(8))) short short8;
typedef __attribute__((ext_vector_type(4))) float floatx4;
typedef __attribute__((ext_vector_type(4))) unsigned int uintx4;

#define TILE_TRI 576   // triangles per block (12 waves * 48)
#define WAVE_TRI 48    // triangles per wave (3 m-tiles of 16)
#define NTHREADS 768   // 12 waves

// fp32 -> bf16 conversion of f_edge into workspace (8 elems/thread)
__global__ __launch_bounds__(256)
void cvt_bf16(const float* __restrict__ src, unsigned short* __restrict__ dst, int n8)
{
    int i = blockIdx.x * 256 + threadIdx.x;
    if (i >= n8) return;
    const float* s = src + (size_t)i * 8;
    unsigned short tmp[8] __attribute__((aligned(16)));
#pragma unroll
    for (int j = 0; j < 8; ++j) {
        __hip_bfloat16 b = __float2bfloat16(s[j]);
        tmp[j] = *(unsigned short*)&b;
    }
    *(uintx4*)(dst + (size_t)i * 8) = *(const uintx4*)tmp;
}

// GEMM (T x 384) @ (384 x 128) with gather on A, fused bias+GELU, scatter-add by dst.
// A comes from the bf16 copy of f_edge; W (fp32) is converted during LDS staging.
// W staged in LDS in MFMA B-fragment order, 2 K-phases of 48KB each.
__global__ __launch_bounds__(NTHREADS, 3)
void tri_gemm_scatter(const unsigned short* __restrict__ fe,   // bf16 bits, E*128
                      const float* __restrict__ Wg,            // fp32, 384*128 row-major
                      const float* __restrict__ bias,          // fp32, 128
                      const int* __restrict__ tri,             // T*3 int32
                      float* __restrict__ seg,                 // E*128 fp32 accum
                      float* __restrict__ cnt,                 // E fp32 counts
                      int E, int T)
{
    __shared__ uintx4 ldsW[3072];   // 48 KB: 6 ko x 8 nt fragment blocks of 1KB

    const int tid  = threadIdx.x;
    const int wv   = tid >> 6;
    const int lane = tid & 63;
    const int col  = lane & 15;
    const int quad = lane >> 4;
    const int tb   = blockIdx.x * TILE_TRI + wv * WAVE_TRI;

    // Per-lane edge-row byte offsets for the 3 m-tiles (lane&15 selects triangle)
    unsigned int offs[3][3];
#pragma unroll
    for (int mi = 0; mi < 3; ++mi) {
        int t  = tb + mi * 16 + col;
        int tc = t < T ? t : 0;
        offs[mi][0] = (unsigned)tri[tc * 3 + 0] * 256u;
        offs[mi][1] = (unsigned)tri[tc * 3 + 1] * 256u;
        offs[mi][2] = (unsigned)tri[tc * 3 + 2] * 256u;
    }
    const char* feb = (const char*)fe;

    floatx4 acc[3][8];
#pragma unroll
    for (int mi = 0; mi < 3; ++mi)
#pragma unroll
        for (int nt = 0; nt < 8; ++nt) acc[mi][nt] = (floatx4)0.0f;

#pragma unroll 1
    for (int p = 0; p < 2; ++p) {
        if (p) __syncthreads();   // all waves done reading phase-0 LDS
        // Stage 192 rows of W (fp32 -> bf16) into fragment-ordered LDS.
        // Element (k,n): frag = (k_local>>5)*8 + (n>>4); slot = (n&15) | (((k_local>>3)&3)<<4)
        for (int g = tid; g < 3072; g += NTHREADS) {
            int n  = g & 127;
            int kk = g >> 7;              // 0..23 (groups of 8 k)
            int kb = p * 192 + kk * 8;
            unsigned short tmp[8] __attribute__((aligned(16)));
#pragma unroll
            for (int j = 0; j < 8; ++j) {
                __hip_bfloat16 bb = __float2bfloat16(Wg[(kb + j) * 128 + n]);
                tmp[j] = *(unsigned short*)&bb;
            }
            int fragidx = (kk >> 2) * 8 + (n >> 4);
            int slot    = (n & 15) | ((kk & 3) << 4);
            ldsW[fragidx * 64 + slot] = *(const uintx4*)tmp;
        }
        __syncthreads();

#pragma unroll
        for (int kol = 0; kol < 6; ++kol) {
            int ko  = p * 6 + kol;               // global 32-wide K step, 0..11
            int sgi = ko >> 2;                   // which of the 3 edge segments
            int o   = ((ko & 3) << 6) + (quad << 4);  // byte offset within 256B bf16 row
            short8 a[3];
#pragma unroll
            for (int mi = 0; mi < 3; ++mi)
                a[mi] = *(const short8*)(feb + offs[mi][sgi] + o);
#pragma unroll
            for (int nt = 0; nt < 8; ++nt) {
                short8 bf = *(const short8*)&ldsW[(kol * 8 + nt) * 64 + lane];
#pragma unroll
                for (int mi = 0; mi < 3; ++mi)
                    acc[mi][nt] = __builtin_amdgcn_mfma_f32_16x16x32_bf16(
                        a[mi], bf, acc[mi][nt], 0, 0, 0);
            }
        }
    }

    // Epilogue: bias + exact GELU + atomic scatter by dst
    float bv[8];
#pragma unroll
    for (int nt = 0; nt < 8; ++nt) bv[nt] = bias[nt * 16 + col];

#pragma unroll
    for (int mi = 0; mi < 3; ++mi) {
#pragma unroll
        for (int r = 0; r < 4; ++r) {
            int t = tb + mi * 16 + quad * 4 + r;   // D row = quad*4 + reg
            if (t < T) {
                int d = tri[t * 3 + 2];
                float* srow = seg + (size_t)d * 128;
#pragma unroll
                for (int nt = 0; nt < 8; ++nt) {
                    float x = acc[mi][nt][r] + bv[nt];
                    float h = 0.5f * x * (1.0f + erff(x * 0.70710678118654752f));
                    atomicAdd(srow + nt * 16 + col, h);
                }
                if (col == 0) atomicAdd(cnt + d, 1.0f);
            }
        }
    }
}

// Per-edge mean + LayerNorm, one wave per row, lane covers cols {lane, lane+64}
__global__ __launch_bounds__(256)
void ln_kernel(const float* __restrict__ seg, const float* __restrict__ cnt,
               const float* __restrict__ gamma, const float* __restrict__ beta,
               float* __restrict__ out, int E)
{
    int lane = threadIdx.x & 63;
    int row  = blockIdx.x * 4 + (threadIdx.x >> 6);
    if (row >= E) return;
    const float* s = seg + (size_t)row * 128;
    float inv = 1.0f / fmaxf(cnt[row], 1.0f);
    float x0 = s[lane] * inv;
    float x1 = s[lane + 64] * inv;
    float t = x0 + x1;
#pragma unroll
    for (int o = 32; o > 0; o >>= 1) t += __shfl_xor(t, o);
    float mu = t * (1.0f / 128.0f);
    float d0 = x0 - mu, d1 = x1 - mu;
    float v = d0 * d0 + d1 * d1;
#pragma unroll
    for (int o = 32; o > 0; o >>= 1) v += __shfl_xor(v, o);
    float rstd = rsqrtf(v * (1.0f / 128.0f) + 1e-5f);
    float y0 = d0 * rstd * gamma[lane] + beta[lane];
    float y1 = d1 * rstd * gamma[lane + 64] + beta[lane + 64];
    out[(size_t)row * 128 + lane]      = y0;
    out[(size_t)row * 128 + 64 + lane] = y1;
}

extern "C" void kernel_launch(void* const* d_in, const int* in_sizes, int n_in,
                              void* d_out, int out_size, void* d_ws, size_t ws_size,
                              hipStream_t stream)
{
    const float* fe_f  = (const float*)d_in[0];
    const float* Wg    = (const float*)d_in[1];
    const float* bias  = (const float*)d_in[2];
    const float* gamma = (const float*)d_in[3];
    const float* beta  = (const float*)d_in[4];
    const int*   tri   = (const int*)d_in[5];

    int E = in_sizes[0] / 128;
    int T = in_sizes[5] / 3;

    // ws layout: seg (E*128 f32) | cnt (E f32) | fe_bf16 (E*128 bf16)
    float* seg = (float*)d_ws;
    float* cnt = seg + (size_t)E * 128;
    unsigned short* febf = (unsigned short*)(cnt + E);

    // zero accumulators (seg + cnt); ws is poisoned 0xAA
    hipMemsetAsync(d_ws, 0, ((size_t)E * 128 + E) * sizeof(float), stream);

    // convert f_edge fp32 -> bf16
    int n8 = E * 128 / 8;
    cvt_bf16<<<(n8 + 255) / 256, 256, 0, stream>>>(fe_f, febf, n8);

    int nblk = (T + TILE_TRI - 1) / TILE_TRI;
    tri_gemm_scatter<<<nblk, NTHREADS, 0, stream>>>(febf, Wg, bias, tri, seg, cnt, E, T);

    ln_kernel<<<(E + 3) / 4, 256, 0, stream>>>(seg, cnt, gamma, beta,
                                               (float*)d_out, E);
}

// Round 3
// 258.550 us; speedup vs baseline: 1.3853x; 1.3853x over previous
//
#include <hip/hip_runtime.h>
#include <hip/hip_bf16.h>

typedef __attribute__((ext_vector_type(8))) short short8;
typedef __attribute__((ext_vector_type(4))) float floatx4;
typedef __attribute__((ext_vector_type(4))) unsigned int uintx4;

#define TILE_TRI 576   // triangles per block (12 waves * 48)
#define WAVE_TRI 48    // triangles per wave (3 m-tiles of 16)
#define NTHREADS 768   // 12 waves

// fast GELU: x * (1 - 1/(exp(2u)+1)), u = 0.79788456*(x + 0.044715 x^3)
// abs err vs exact-erf GELU ~3e-3, far under the 0.149 output threshold.
__device__ __forceinline__ float gelu_fast(float x)
{
    float u = 0.7978845608f * x * (1.0f + 0.044715f * x * x);
    float e = __builtin_amdgcn_exp2f(2.885390082f * u);   // exp(2u)
    return x - x * __builtin_amdgcn_rcpf(e + 1.0f);
}

// fp32 -> bf16 conversion of f_edge into workspace (8 elems/thread)
__global__ __launch_bounds__(256)
void cvt_bf16(const float* __restrict__ src, unsigned short* __restrict__ dst, int n8)
{
    int i = blockIdx.x * 256 + threadIdx.x;
    if (i >= n8) return;
    const float* s = src + (size_t)i * 8;
    unsigned short tmp[8] __attribute__((aligned(16)));
#pragma unroll
    for (int j = 0; j < 8; ++j) {
        __hip_bfloat16 b = __float2bfloat16(s[j]);
        tmp[j] = *(unsigned short*)&b;
    }
    *(uintx4*)(dst + (size_t)i * 8) = *(const uintx4*)tmp;
}

// Per-edge linked list over triangles keyed by dst = tri[:,2]. 400K atomics total.
__global__ __launch_bounds__(256)
void build_links(const int* __restrict__ tri, int* __restrict__ head,
                 int* __restrict__ next, int T)
{
    int i = blockIdx.x * 256 + threadIdx.x;
    if (i < T) next[i] = atomicExch(&head[tri[i * 3 + 2]], i);
}

// GEMM (T x 384) @ (384 x 128) with gather on A, fused bias+GELU.
// Output h written as bf16 in MFMA C-layout order: row t, physical elem col*8+nt
// (col=lane&15). Each lane stores its 8 accs as ONE 16B store; a quad's 16 lanes
// cover the full 256B row contiguously. No atomics.
__global__ __launch_bounds__(NTHREADS, 3)
void tri_gemm_ht(const unsigned short* __restrict__ fe,   // bf16 bits, E*128
                 const float* __restrict__ Wg,            // fp32, 384*128 row-major
                 const float* __restrict__ bias,          // fp32, 128
                 const int* __restrict__ tri,             // T*3 int32
                 unsigned short* __restrict__ ht,         // bf16 bits, T*128 (permuted)
                 int E, int T)
{
    __shared__ uintx4 ldsW[3072];   // 48 KB: 6 ko x 8 nt fragment blocks of 1KB

    const int tid  = threadIdx.x;
    const int wv   = tid >> 6;
    const int lane = tid & 63;
    const int col  = lane & 15;
    const int quad = lane >> 4;
    const int tb   = blockIdx.x * TILE_TRI + wv * WAVE_TRI;

    unsigned int offs[3][3];
#pragma unroll
    for (int mi = 0; mi < 3; ++mi) {
        int t  = tb + mi * 16 + col;
        int tc = t < T ? t : 0;
        offs[mi][0] = (unsigned)tri[tc * 3 + 0] * 256u;
        offs[mi][1] = (unsigned)tri[tc * 3 + 1] * 256u;
        offs[mi][2] = (unsigned)tri[tc * 3 + 2] * 256u;
    }
    const char* feb = (const char*)fe;

    floatx4 acc[3][8];
#pragma unroll
    for (int mi = 0; mi < 3; ++mi)
#pragma unroll
        for (int nt = 0; nt < 8; ++nt) acc[mi][nt] = (floatx4)0.0f;

#pragma unroll 1
    for (int p = 0; p < 2; ++p) {
        if (p) __syncthreads();
        // Stage 192 rows of W (fp32 -> bf16) into fragment-ordered LDS.
        for (int g = tid; g < 3072; g += NTHREADS) {
            int n  = g & 127;
            int kk = g >> 7;              // 0..23 (groups of 8 k)
            int kb = p * 192 + kk * 8;
            unsigned short tmp[8] __attribute__((aligned(16)));
#pragma unroll
            for (int j = 0; j < 8; ++j) {
                __hip_bfloat16 bb = __float2bfloat16(Wg[(kb + j) * 128 + n]);
                tmp[j] = *(unsigned short*)&bb;
            }
            int fragidx = (kk >> 2) * 8 + (n >> 4);
            int slot    = (n & 15) | ((kk & 3) << 4);
            ldsW[fragidx * 64 + slot] = *(const uintx4*)tmp;
        }
        __syncthreads();

#pragma unroll
        for (int kol = 0; kol < 6; ++kol) {
            int ko  = p * 6 + kol;
            int sgi = ko >> 2;
            int o   = ((ko & 3) << 6) + (quad << 4);
            short8 a[3];
#pragma unroll
            for (int mi = 0; mi < 3; ++mi)
                a[mi] = *(const short8*)(feb + offs[mi][sgi] + o);
#pragma unroll
            for (int nt = 0; nt < 8; ++nt) {
                short8 bf = *(const short8*)&ldsW[(kol * 8 + nt) * 64 + lane];
#pragma unroll
                for (int mi = 0; mi < 3; ++mi)
                    acc[mi][nt] = __builtin_amdgcn_mfma_f32_16x16x32_bf16(
                        a[mi], bf, acc[mi][nt], 0, 0, 0);
            }
        }
    }

    // Epilogue: bias + fast GELU, pack 8 bf16, one 16B store per (mi,r)
    float bv[8];
#pragma unroll
    for (int nt = 0; nt < 8; ++nt) bv[nt] = bias[nt * 16 + col];

#pragma unroll
    for (int mi = 0; mi < 3; ++mi) {
#pragma unroll
        for (int r = 0; r < 4; ++r) {
            int t = tb + mi * 16 + quad * 4 + r;   // D row = quad*4 + reg
            if (t < T) {
                unsigned short pk[8] __attribute__((aligned(16)));
#pragma unroll
                for (int nt = 0; nt < 8; ++nt) {
                    float h = gelu_fast(acc[mi][nt][r] + bv[nt]);
                    __hip_bfloat16 hb = __float2bfloat16(h);
                    pk[nt] = *(unsigned short*)&hb;
                }
                *(uintx4*)(ht + (size_t)t * 128 + col * 8) = *(const uintx4*)pk;
            }
        }
    }
}

// Per-edge mean + LayerNorm, one wave per row. Walk the triangle linked list,
// each lane reads one bf16x2 (4B) of the 256B permuted ht row -> fully coalesced.
// Lane (col=l&15,q=l>>4) owns logical cols j0=32q+col, j1=j0+16 (LN reductions
// are permutation-invariant; gamma/beta/out indexed at j -> coalesced stores).
__global__ __launch_bounds__(256)
void mean_ln(const unsigned short* __restrict__ ht,
             const int* __restrict__ head, const int* __restrict__ next,
             const float* __restrict__ gamma, const float* __restrict__ beta,
             float* __restrict__ out, int E)
{
    int lane = threadIdx.x & 63;
    int row  = blockIdx.x * 4 + (threadIdx.x >> 6);
    if (row >= E) return;
    int col = lane & 15, q = lane >> 4;
    const char* htb = (const char*)ht;
    int boff = (col << 4) + (q << 2);   // byte offset within 256B row

    int t = head[row];
    float x0 = 0.0f, x1 = 0.0f, c = 0.0f;
    while (t >= 0) {
        unsigned int w = *(const unsigned int*)(htb + (size_t)t * 256 + boff);
        x0 += __uint_as_float(w << 16);          // physical elem col*8+2q  -> j0
        x1 += __uint_as_float(w & 0xffff0000u);  // physical elem col*8+2q+1-> j1
        c += 1.0f;
        t = next[t];
    }
    float inv = 1.0f / fmaxf(c, 1.0f);
    float m0 = x0 * inv, m1 = x1 * inv;
    float s = m0 + m1;
#pragma unroll
    for (int o = 32; o > 0; o >>= 1) s += __shfl_xor(s, o);
    float mu = s * (1.0f / 128.0f);
    float d0 = m0 - mu, d1 = m1 - mu;
    float v = d0 * d0 + d1 * d1;
#pragma unroll
    for (int o = 32; o > 0; o >>= 1) v += __shfl_xor(v, o);
    float rstd = rsqrtf(v * (1.0f / 128.0f) + 1e-5f);
    int j0 = q * 32 + col, j1 = j0 + 16;
    out[(size_t)row * 128 + j0] = d0 * rstd * gamma[j0] + beta[j0];
    out[(size_t)row * 128 + j1] = d1 * rstd * gamma[j1] + beta[j1];
}

extern "C" void kernel_launch(void* const* d_in, const int* in_sizes, int n_in,
                              void* d_out, int out_size, void* d_ws, size_t ws_size,
                              hipStream_t stream)
{
    const float* fe_f  = (const float*)d_in[0];
    const float* Wg    = (const float*)d_in[1];
    const float* bias  = (const float*)d_in[2];
    const float* gamma = (const float*)d_in[3];
    const float* beta  = (const float*)d_in[4];
    const int*   tri   = (const int*)d_in[5];

    int E = in_sizes[0] / 128;
    int T = in_sizes[5] / 3;

    // ws layout: ht (T*128 bf16) | febf (E*128 bf16) | head (E i32) | next (T i32)
    unsigned short* ht   = (unsigned short*)d_ws;
    unsigned short* febf = ht + (size_t)T * 128;
    int* head = (int*)(febf + (size_t)E * 128);
    int* next = head + E;

    hipMemsetAsync(head, 0xFF, (size_t)E * sizeof(int), stream);   // head = -1

    int n8 = E * 128 / 8;
    cvt_bf16<<<(n8 + 255) / 256, 256, 0, stream>>>(fe_f, febf, n8);

    build_links<<<(T + 255) / 256, 256, 0, stream>>>(tri, head, next, T);

    int nblk = (T + TILE_TRI - 1) / TILE_TRI;
    tri_gemm_ht<<<nblk, NTHREADS, 0, stream>>>(febf, Wg, bias, tri, ht, E, T);

    mean_ln<<<(E + 3) / 4, 256, 0, stream>>>(ht, head, next, gamma, beta,
                                             (float*)d_out, E);
}